// Round 1
// baseline (115.049 us; speedup 1.0000x reference)
//
#include <hip/hip_runtime.h>
#include <hip/hip_fp16.h>

#define NATOM 8192
#define FR    128
#define LH1   128
#define LH2   64
#define NSEG  64
#define PB    256     // pair-kernel blocks
#define PT    1024    // pair-kernel threads/block
#define PPT   16      // pairs per thread

// ---------------- kernel 0: transpose weights into ws ----------------
// ws layout (floats): [0)=W1s^T 16384, [16384)=W2s^T 8192, [24576)=W1e^T 16384,
// [40960)=W2e^T 8192, [49152)=sig15 8192, [57344)=qv 8192, [65536)=blocksums PB*64
__global__ __launch_bounds__(256) void k_transpose(
    const float* __restrict__ w1s, const float* __restrict__ w2s,
    const float* __restrict__ w1e, const float* __restrict__ w2e,
    float* __restrict__ ws)
{
    int t = blockIdx.x * 256 + threadIdx.x;
    if (t < 16384)       { int k = t >> 7, c = t & 127; ws[c * 128 + k] = w1s[t]; }
    else if (t < 24576)  { int u = t - 16384; int k = u >> 6, c = u & 63;  ws[16384 + c * 128 + k] = w2s[u]; }
    else if (t < 40960)  { int u = t - 24576; int k = u >> 7, c = u & 127; ws[24576 + c * 128 + k] = w1e[u]; }
    else if (t < 49152)  { int u = t - 40960; int k = u >> 6, c = u & 63;  ws[40960 + c * 128 + k] = w2e[u]; }
}

// ---------------- kernel 1: per-atom MLPs ----------------
// grid (128, 2): x = atom group of 64 (lane = atom), y = path (0 sigma, 1 eps)
// wave w owns output columns [w*32, w*32+32) of layer1 and [w*16, w*16+16) of layer2.
// Weight reads use uniform indices -> s_load; r row lives per-lane in VGPRs.
__global__ __launch_bounds__(256) void k_mlp(
    const float* __restrict__ r, const float* __restrict__ wsw,
    const float* __restrict__ b1s, const float* __restrict__ b2s,
    const float* __restrict__ w3s, const float* __restrict__ b3s,
    const float* __restrict__ b1e, const float* __restrict__ b2e,
    const float* __restrict__ w3e, const float* __restrict__ b3e,
    float* __restrict__ sig15, float* __restrict__ qv)
{
    const int path = blockIdx.y;
    const float* __restrict__ w1 = wsw + (path ? 24576 : 0);
    const float* __restrict__ w2 = wsw + (path ? 40960 : 16384);
    const float* __restrict__ b1 = path ? b1e : b1s;
    const float* __restrict__ b2 = path ? b2e : b2s;
    const float* __restrict__ w3 = path ? w3e : w3s;
    const float* __restrict__ b3 = path ? b3e : b3s;

    const int lane = threadIdx.x & 63;
    const int wv = __builtin_amdgcn_readfirstlane(threadIdx.x >> 6);
    const int a = blockIdx.x * 64 + lane;

    __shared__ float h1s[LH1][64];
    __shared__ float p3s[4][64];

    // load this lane's feature row (128 f32) into registers
    float rr[FR];
    const float4* rp = (const float4*)(r + (size_t)a * FR);
#pragma unroll
    for (int i = 0; i < FR / 4; ++i) {
        float4 v = rp[i];
        rr[4*i] = v.x; rr[4*i+1] = v.y; rr[4*i+2] = v.z; rr[4*i+3] = v.w;
    }

    // layer 1: 32 columns per wave, full K, 4 partial chains for ILP
#pragma unroll 2
    for (int ci = 0; ci < 32; ++ci) {
        const int c = wv * 32 + ci;
        const float* __restrict__ wr = w1 + c * FR;   // uniform -> s_load
        float s0 = 0.f, s1 = 0.f, s2 = 0.f, s3 = 0.f;
#pragma unroll
        for (int k = 0; k < FR; k += 4) {
            s0 = fmaf(rr[k+0], wr[k+0], s0);
            s1 = fmaf(rr[k+1], wr[k+1], s1);
            s2 = fmaf(rr[k+2], wr[k+2], s2);
            s3 = fmaf(rr[k+3], wr[k+3], s3);
        }
        h1s[c][lane] = tanhf((s0 + s1) + (s2 + s3) + b1[c]);
    }
    __syncthreads();

    // pull full h1 vector into registers (conflict-free: bank = lane%32, 2-way free)
    float hh[LH1];
#pragma unroll
    for (int k = 0; k < LH1; ++k) hh[k] = h1s[k][lane];

    // layer 2 (16 cols/wave) fused with layer-3 partial dot
    float p3 = 0.f;
#pragma unroll 2
    for (int ci = 0; ci < 16; ++ci) {
        const int c = wv * 16 + ci;
        const float* __restrict__ wr = w2 + c * LH1;  // uniform -> s_load
        float s0 = 0.f, s1 = 0.f, s2 = 0.f, s3 = 0.f;
#pragma unroll
        for (int k = 0; k < LH1; k += 4) {
            s0 = fmaf(hh[k+0], wr[k+0], s0);
            s1 = fmaf(hh[k+1], wr[k+1], s1);
            s2 = fmaf(hh[k+2], wr[k+2], s2);
            s3 = fmaf(hh[k+3], wr[k+3], s3);
        }
        float h = tanhf((s0 + s1) + (s2 + s3) + b2[c]);
        p3 = fmaf(h, w3[c], p3);
    }
    p3s[wv][lane] = p3;
    __syncthreads();

    if (wv == 0) {
        float m = ((p3s[0][lane] + p3s[1][lane]) + (p3s[2][lane] + p3s[3][lane])) + b3[0];
        if (path == 0) {
            float sg = fmaf(10.f * m, m, 4.f);       // sigma = 4 + 10 m^2
            sig15[a] = sg * sqrtf(sg);               // sigma^1.5
        } else {
            qv[a] = 0.31622776601683794f * fabsf(m); // sqrt(0.1)*|m| = sqrt(eps)
        }
    }
}

// ---------------- kernel 2: pair energies ----------------
__device__ __forceinline__ float pair_e(const float4* atomd, int ia, int ib)
{
    float4 A = atomd[ia], B = atomd[ib];
    float dx = A.x - B.x, dy = A.y - B.y, dz = A.z - B.z;
    float D2 = fmaf(dx, dx, fmaf(dy, dy, dz * dz));
    float inv = __builtin_amdgcn_rcpf(D2);
    float inv3 = inv * inv * inv;
    __half2 ha = __builtin_bit_cast(__half2, A.w);
    __half2 hb = __builtin_bit_cast(__half2, B.w);
    float pp = __low2float(ha) * __low2float(hb);    // sig_i^1.5 * sig_j^1.5
    float qq = __high2float(ha) * __high2float(hb);  // eps_mixed
    float s6 = pp * pp * inv3;                       // (sig_i*sig_j)^3 / D2^3
    return 4.f * qq * (s6 * s6 - s6);
}

__global__ __launch_bounds__(PT, 1) void k_pair(
    const float* __restrict__ xyz, const int* __restrict__ pairs,
    const int* __restrict__ num_pairs,
    const float* __restrict__ sig15, const float* __restrict__ qv,
    float* __restrict__ blocksums, int P)
{
    extern __shared__ char smem[];
    float4* atomd = (float4*)smem;                         // 8192 * 16B = 128 KiB
    int*    off   = (int*)(smem + NATOM * 16);             // 65 ints (+pad)
    float*  bsum  = (float*)(smem + NATOM * 16 + 68 * 4);  // 64 floats

    const int tid = threadIdx.x;

    // stage atom data {x,y,z, pack(f16 p, f16 q)} into LDS
    for (int i = tid; i < NATOM; i += PT) {
        float x = xyz[3 * i], y = xyz[3 * i + 1], z = xyz[3 * i + 2];
        __half2 pq = __halves2half2(__float2half(sig15[i]), __float2half(qv[i]));
        atomd[i] = make_float4(x, y, z, __builtin_bit_cast(float, pq));
    }
    if (tid < NSEG) { off[tid + 1] = num_pairs[tid]; bsum[tid] = 0.f; }
    if (tid == PT - 1) off[0] = 0;
    __syncthreads();
    if (tid == 0) { int run = 0; for (int b = 1; b <= NSEG; ++b) { run += off[b]; off[b] = run; } }
    __syncthreads();

    const int base = (blockIdx.x * PT + tid) * PPT;
    const bool fast = (base + PPT <= P);

    if (__all(fast)) {
        // prefetch 16 pairs (32 ints) as int4s, all statically indexed
        int pr2[PPT * 2];
        const int4* pp4 = (const int4*)(pairs + (size_t)base * 2);
#pragma unroll
        for (int i = 0; i < PPT / 2; ++i) {
            int4 v = pp4[i];
            pr2[4*i] = v.x; pr2[4*i+1] = v.y; pr2[4*i+2] = v.z; pr2[4*i+3] = v.w;
        }
        // binary search: largest s with off[s] <= base
        int s = 0;
#pragma unroll
        for (int st = 32; st; st >>= 1) { int ns = s + st; if (ns <= NSEG - 1 && off[ns] <= base) s = ns; }
        int off_next = off[s + 1];
        float acc = 0.f;
#pragma unroll
        for (int i = 0; i < PPT; ++i) {
            int idx = base + i;
            while (s < NSEG - 1 && idx >= off_next) {   // segment boundary (rare)
                if (acc != 0.f) atomicAdd(&bsum[s], acc);
                acc = 0.f; ++s; off_next = off[s + 1];
            }
            acc += pair_e(atomd, pr2[2 * i], pr2[2 * i + 1]);
        }
        // wave-level reduce when the whole wave sits in one segment (common case)
        int s0 = __builtin_amdgcn_readfirstlane(s);
        if (__all(s == s0)) {
            float v = acc;
#pragma unroll
            for (int o = 32; o; o >>= 1) v += __shfl_xor(v, o);
            if ((tid & 63) == 0) atomicAdd(&bsum[s0], v);
        } else {
            atomicAdd(&bsum[s], acc);
        }
    } else if (base < P) {
        // generic tail path (not hit with P = 4194304)
        int s = 0;
#pragma unroll
        for (int st = 32; st; st >>= 1) { int ns = s + st; if (ns <= NSEG - 1 && off[ns] <= base) s = ns; }
        int off_next = off[s + 1];
        float acc = 0.f;
        for (int i = 0; i < PPT; ++i) {
            int idx = base + i;
            if (idx >= P) break;
            while (s < NSEG - 1 && idx >= off_next) {
                if (acc != 0.f) atomicAdd(&bsum[s], acc);
                acc = 0.f; ++s; off_next = off[s + 1];
            }
            acc += pair_e(atomd, pairs[2 * (size_t)idx], pairs[2 * (size_t)idx + 1]);
        }
        if (acc != 0.f) atomicAdd(&bsum[s], acc);
    }
    __syncthreads();
    if (tid < NSEG) blocksums[blockIdx.x * NSEG + tid] = bsum[tid];
}

// ---------------- kernel 3: deterministic final reduce ----------------
__global__ __launch_bounds__(256) void k_reduce(const float* __restrict__ bs, float* __restrict__ out)
{
    __shared__ float red[4][NSEG];
    int b = threadIdx.x & 63, part = threadIdx.x >> 6;
    float s = 0.f;
    for (int j = part; j < PB; j += 4) s += bs[(size_t)j * NSEG + b];
    red[part][b] = s;
    __syncthreads();
    if (threadIdx.x < NSEG) out[b] = (red[0][b] + red[1][b]) + (red[2][b] + red[3][b]);
}

extern "C" void kernel_launch(void* const* d_in, const int* in_sizes, int n_in,
                              void* d_out, int out_size, void* d_ws, size_t ws_size,
                              hipStream_t stream)
{
    const float* r    = (const float*)d_in[0];
    const float* xyz  = (const float*)d_in[1];
    const int*   prs  = (const int*)d_in[2];
    const int*   np   = (const int*)d_in[3];
    const float* sW1  = (const float*)d_in[4];
    const float* sb1  = (const float*)d_in[5];
    const float* sW2  = (const float*)d_in[6];
    const float* sb2  = (const float*)d_in[7];
    const float* sW3  = (const float*)d_in[8];
    const float* sb3  = (const float*)d_in[9];
    const float* eW1  = (const float*)d_in[10];
    const float* eb1  = (const float*)d_in[11];
    const float* eW2  = (const float*)d_in[12];
    const float* eb2  = (const float*)d_in[13];
    const float* eW3  = (const float*)d_in[14];
    const float* eb3  = (const float*)d_in[15];
    float* out = (float*)d_out;
    float* ws  = (float*)d_ws;
    const int P = in_sizes[2] / 2;

    float* wsw   = ws;            // 49152 floats of transposed weights
    float* sig15 = ws + 49152;    // 8192
    float* qvv   = ws + 57344;    // 8192
    float* bsums = ws + 65536;    // PB*64

    k_transpose<<<192, 256, 0, stream>>>(sW1, sW2, eW1, eW2, wsw);
    k_mlp<<<dim3(NATOM / 64, 2), 256, 0, stream>>>(r, wsw, sb1, sb2, sW3, sb3,
                                                   eb1, eb2, eW3, eb3, sig15, qvv);
    size_t smem = (size_t)NATOM * 16 + 68 * 4 + NSEG * 4;   // 131,600 B
    hipFuncSetAttribute((const void*)k_pair, hipFuncAttributeMaxDynamicSharedMemorySize, (int)smem);
    k_pair<<<PB, PT, smem, stream>>>(xyz, prs, np, sig15, qvv, bsums, P);
    k_reduce<<<1, 256, 0, stream>>>(bsums, out);
}

// Round 2
// 60.850 us; speedup vs baseline: 1.8907x; 1.8907x over previous
//
#include <hip/hip_runtime.h>
#include <hip/hip_fp16.h>

#define NATOM 8192
#define FR    128
#define LH1   128
#define LH2   64
#define NSEG  64
#define PB    256     // pair-kernel blocks
#define PT    1024    // pair-kernel threads/block
#define PPT   16      // pairs per thread

// fast tanh: 1 - 2/(e^{2x}+1); saturates to +-1 for large |x| (inf-safe)
__device__ __forceinline__ float fast_tanh(float x)
{
    float t = __expf(2.f * x);
    return 1.f - 2.f * __builtin_amdgcn_rcpf(t + 1.f);
}

// ---------------- kernel 1: per-atom MLPs ----------------
// grid (128, 2): x = atom group of 64 (lane = atom), y = path (0 sigma, 1 eps)
// 512 threads = 8 waves. Wave wv owns cols [wv*16,+16) of layer1, [wv*8,+8) of layer2.
// r staged k-major in LDS (XOR-swizzled); weights read at uniform addresses -> s_load
// broadcasts (contiguous 64B per k since W is [k][c] row-major). Per-column
// accumulators live in registers (16 VGPRs), so no per-lane spills.
__global__ __launch_bounds__(512) void k_mlp(
    const float* __restrict__ r,
    const float* __restrict__ w1s, const float* __restrict__ b1s,
    const float* __restrict__ w2s, const float* __restrict__ b2s,
    const float* __restrict__ w3s, const float* __restrict__ b3s,
    const float* __restrict__ w1e, const float* __restrict__ b1e,
    const float* __restrict__ w2e, const float* __restrict__ b2e,
    const float* __restrict__ w3e, const float* __restrict__ b3e,
    float* __restrict__ sig15, float* __restrict__ qv)
{
    const int path = blockIdx.y;
    const float* __restrict__ w1 = path ? w1e : w1s;
    const float* __restrict__ b1 = path ? b1e : b1s;
    const float* __restrict__ w2 = path ? w2e : w2s;
    const float* __restrict__ b2 = path ? b2e : b2s;
    const float* __restrict__ w3 = path ? w3e : w3s;
    const float* __restrict__ b3 = path ? b3e : b3s;

    const int tid  = threadIdx.x;
    const int lane = tid & 63;
    const int wv   = __builtin_amdgcn_readfirstlane(tid >> 6);

    __shared__ float rT[FR * 64];     // rT[k][atom^(k>>2)]; later reused as h1T[c][atom]
    __shared__ float p3s[8][64];

    // ---- stage r tile: 64 atoms x 128 k, k-major with XOR swizzle ----
    // thread t, iter i: float4 index f = i*512 + t; atom = f>>5, k0 = (f&31)*4.
    // write bank = (atom ^ (f&31)) % 32 -> conflict-free halves.
    {
        const float4* rp = (const float4*)(r + (size_t)blockIdx.x * 64 * FR);
#pragma unroll
        for (int i = 0; i < 4; ++i) {
            int f = i * 512 + tid;
            float4 v = rp[f];
            int atom = f >> 5, k0 = (f & 31) * 4, sw = f & 31;
            rT[(k0 + 0) * 64 + (atom ^ sw)] = v.x;
            rT[(k0 + 1) * 64 + (atom ^ sw)] = v.y;
            rT[(k0 + 2) * 64 + (atom ^ sw)] = v.z;
            rT[(k0 + 3) * 64 + (atom ^ sw)] = v.w;
        }
    }
    __syncthreads();

    // ---- layer 1: 16 cols per wave ----
    float acc[16];
#pragma unroll
    for (int ci = 0; ci < 16; ++ci) acc[ci] = 0.f;
    {
        const float* __restrict__ w1p = w1 + wv * 16;   // uniform base
#pragma unroll 4
        for (int k = 0; k < FR; ++k) {
            float rv = rT[k * 64 + (lane ^ (k >> 2))];
            const float* __restrict__ wk = w1p + k * LH1;   // 16 contiguous floats -> s_load
#pragma unroll
            for (int ci = 0; ci < 16; ++ci) acc[ci] = fmaf(rv, wk[ci], acc[ci]);
        }
    }
    __syncthreads();   // all rT reads done; buffer about to be reused for h1

    // ---- tanh + write h1 (h1T[c][atom], conflict-free) ----
#pragma unroll
    for (int ci = 0; ci < 16; ++ci) {
        int c = wv * 16 + ci;
        rT[c * 64 + lane] = fast_tanh(acc[ci] + b1[c]);
    }
    __syncthreads();

    // ---- layer 2 (8 cols/wave) fused with layer-3 partial dot ----
    float acc2[8];
#pragma unroll
    for (int ci = 0; ci < 8; ++ci) acc2[ci] = 0.f;
    {
#pragma unroll 4
        for (int k = 0; k < LH1; ++k) {
            float hv = rT[k * 64 + lane];
            const float* __restrict__ wk = w2 + k * LH2 + wv * 8;  // 8 contiguous -> s_load
#pragma unroll
            for (int ci = 0; ci < 8; ++ci) acc2[ci] = fmaf(hv, wk[ci], acc2[ci]);
        }
    }
    float p3 = 0.f;
#pragma unroll
    for (int ci = 0; ci < 8; ++ci) {
        int c = wv * 8 + ci;
        p3 = fmaf(fast_tanh(acc2[ci] + b2[c]), w3[c], p3);
    }
    p3s[wv][lane] = p3;
    __syncthreads();

    if (wv == 0) {
        float m = (((p3s[0][lane] + p3s[1][lane]) + (p3s[2][lane] + p3s[3][lane]))
                +  ((p3s[4][lane] + p3s[5][lane]) + (p3s[6][lane] + p3s[7][lane]))) + b3[0];
        int a = blockIdx.x * 64 + lane;
        if (path == 0) {
            float sg = fmaf(10.f * m, m, 4.f);       // sigma = 4 + 10 m^2
            sig15[a] = sg * sqrtf(sg);               // sigma^1.5
        } else {
            qv[a] = 0.31622776601683794f * fabsf(m); // sqrt(0.1)*|m| = sqrt(eps)
        }
    }
}

// ---------------- kernel 2: pair energies ----------------
__device__ __forceinline__ float pair_e(const float4* atomd, int ia, int ib)
{
    float4 A = atomd[ia], B = atomd[ib];
    float dx = A.x - B.x, dy = A.y - B.y, dz = A.z - B.z;
    float D2 = fmaf(dx, dx, fmaf(dy, dy, dz * dz));
    float inv = __builtin_amdgcn_rcpf(D2);
    float inv3 = inv * inv * inv;
    __half2 ha = __builtin_bit_cast(__half2, A.w);
    __half2 hb = __builtin_bit_cast(__half2, B.w);
    float pp = __low2float(ha) * __low2float(hb);    // sig_i^1.5 * sig_j^1.5
    float qq = __high2float(ha) * __high2float(hb);  // eps_mixed
    float s6 = pp * pp * inv3;                       // (sig_i*sig_j)^3 / D2^3
    return 4.f * qq * (s6 * s6 - s6);
}

__global__ __launch_bounds__(PT, 1) void k_pair(
    const float* __restrict__ xyz, const int* __restrict__ pairs,
    const int* __restrict__ num_pairs,
    const float* __restrict__ sig15, const float* __restrict__ qv,
    float* __restrict__ blocksums, int P)
{
    extern __shared__ char smem[];
    float4* atomd = (float4*)smem;                         // 8192 * 16B = 128 KiB
    int*    off   = (int*)(smem + NATOM * 16);             // 65 ints (+pad)
    float*  bsum  = (float*)(smem + NATOM * 16 + 68 * 4);  // 64 floats

    const int tid = threadIdx.x;

    // stage atom data {x,y,z, pack(f16 p, f16 q)} into LDS
    for (int i = tid; i < NATOM; i += PT) {
        float x = xyz[3 * i], y = xyz[3 * i + 1], z = xyz[3 * i + 2];
        __half2 pq = __halves2half2(__float2half(sig15[i]), __float2half(qv[i]));
        atomd[i] = make_float4(x, y, z, __builtin_bit_cast(float, pq));
    }
    if (tid < NSEG) { off[tid + 1] = num_pairs[tid]; bsum[tid] = 0.f; }
    if (tid == PT - 1) off[0] = 0;
    __syncthreads();
    if (tid == 0) { int run = 0; for (int b = 1; b <= NSEG; ++b) { run += off[b]; off[b] = run; } }
    __syncthreads();

    const int base = (blockIdx.x * PT + tid) * PPT;
    const bool fast = (base + PPT <= P);

    if (__all(fast)) {
        int pr2[PPT * 2];
        const int4* pp4 = (const int4*)(pairs + (size_t)base * 2);
#pragma unroll
        for (int i = 0; i < PPT / 2; ++i) {
            int4 v = pp4[i];
            pr2[4*i] = v.x; pr2[4*i+1] = v.y; pr2[4*i+2] = v.z; pr2[4*i+3] = v.w;
        }
        int s = 0;
#pragma unroll
        for (int st = 32; st; st >>= 1) { int ns = s + st; if (ns <= NSEG - 1 && off[ns] <= base) s = ns; }
        int off_next = off[s + 1];
        float acc = 0.f;
#pragma unroll
        for (int i = 0; i < PPT; ++i) {
            int idx = base + i;
            while (s < NSEG - 1 && idx >= off_next) {   // segment boundary (rare)
                if (acc != 0.f) atomicAdd(&bsum[s], acc);
                acc = 0.f; ++s; off_next = off[s + 1];
            }
            acc += pair_e(atomd, pr2[2 * i], pr2[2 * i + 1]);
        }
        int s0 = __builtin_amdgcn_readfirstlane(s);
        if (__all(s == s0)) {
            float v = acc;
#pragma unroll
            for (int o = 32; o; o >>= 1) v += __shfl_xor(v, o);
            if ((tid & 63) == 0) atomicAdd(&bsum[s0], v);
        } else {
            atomicAdd(&bsum[s], acc);
        }
    } else if (base < P) {
        int s = 0;
#pragma unroll
        for (int st = 32; st; st >>= 1) { int ns = s + st; if (ns <= NSEG - 1 && off[ns] <= base) s = ns; }
        int off_next = off[s + 1];
        float acc = 0.f;
        for (int i = 0; i < PPT; ++i) {
            int idx = base + i;
            if (idx >= P) break;
            while (s < NSEG - 1 && idx >= off_next) {
                if (acc != 0.f) atomicAdd(&bsum[s], acc);
                acc = 0.f; ++s; off_next = off[s + 1];
            }
            acc += pair_e(atomd, pairs[2 * (size_t)idx], pairs[2 * (size_t)idx + 1]);
        }
        if (acc != 0.f) atomicAdd(&bsum[s], acc);
    }
    __syncthreads();
    if (tid < NSEG) blocksums[blockIdx.x * NSEG + tid] = bsum[tid];
}

// ---------------- kernel 3: deterministic final reduce ----------------
__global__ __launch_bounds__(256) void k_reduce(const float* __restrict__ bs, float* __restrict__ out)
{
    __shared__ float red[4][NSEG];
    int b = threadIdx.x & 63, part = threadIdx.x >> 6;
    float s = 0.f;
    for (int j = part; j < PB; j += 4) s += bs[(size_t)j * NSEG + b];
    red[part][b] = s;
    __syncthreads();
    if (threadIdx.x < NSEG) out[b] = (red[0][b] + red[1][b]) + (red[2][b] + red[3][b]);
}

extern "C" void kernel_launch(void* const* d_in, const int* in_sizes, int n_in,
                              void* d_out, int out_size, void* d_ws, size_t ws_size,
                              hipStream_t stream)
{
    const float* r    = (const float*)d_in[0];
    const float* xyz  = (const float*)d_in[1];
    const int*   prs  = (const int*)d_in[2];
    const int*   np   = (const int*)d_in[3];
    const float* sW1  = (const float*)d_in[4];
    const float* sb1  = (const float*)d_in[5];
    const float* sW2  = (const float*)d_in[6];
    const float* sb2  = (const float*)d_in[7];
    const float* sW3  = (const float*)d_in[8];
    const float* sb3  = (const float*)d_in[9];
    const float* eW1  = (const float*)d_in[10];
    const float* eb1  = (const float*)d_in[11];
    const float* eW2  = (const float*)d_in[12];
    const float* eb2  = (const float*)d_in[13];
    const float* eW3  = (const float*)d_in[14];
    const float* eb3  = (const float*)d_in[15];
    float* out = (float*)d_out;
    float* ws  = (float*)d_ws;
    const int P = in_sizes[2] / 2;

    float* sig15 = ws;            // 8192
    float* qvv   = ws + 8192;     // 8192
    float* bsums = ws + 16384;    // PB*64

    k_mlp<<<dim3(NATOM / 64, 2), 512, 0, stream>>>(
        r, sW1, sb1, sW2, sb2, sW3, sb3, eW1, eb1, eW2, eb2, eW3, eb3, sig15, qvv);

    size_t smem = (size_t)NATOM * 16 + 68 * 4 + NSEG * 4;   // 131,600 B
    hipFuncSetAttribute((const void*)k_pair, hipFuncAttributeMaxDynamicSharedMemorySize, (int)smem);
    k_pair<<<PB, PT, smem, stream>>>(xyz, prs, np, sig15, qvv, bsums, P);
    k_reduce<<<1, 256, 0, stream>>>(bsums, out);
}